// Round 9
// baseline (134.837 us; speedup 1.0000x reference)
//
#include <hip/hip_runtime.h>
#include <hip/hip_bf16.h>
#include <math.h>

#define BN_EPS 1e-5f

typedef __attribute__((ext_vector_type(8))) short short8;
typedef __attribute__((ext_vector_type(4))) float f32x4;

__device__ __forceinline__ unsigned short bfbits(float f) {
  __hip_bfloat16 h = __float2bfloat16(f);
  return *reinterpret_cast<unsigned short*>(&h);
}
__device__ __forceinline__ float bf2f(unsigned short u) {
  union { unsigned v; float f; } c; c.v = ((unsigned)u) << 16;
  return c.f;
}

// ---------------- Kernel A: prep (blocks 0..15) + pool (blocks 16..2063) ----
__global__ __launch_bounds__(256) void prep_pool_kernel(
    const float* __restrict__ x, float* __restrict__ pooled,
    const float* __restrict__ fc3_w,
    const float* __restrict__ g3, const float* __restrict__ b3,
    const float* __restrict__ m3, const float* __restrict__ v3,
    const float* __restrict__ c1w,
    const float* __restrict__ g1, const float* __restrict__ b1,
    const float* __restrict__ m1, const float* __restrict__ v1,
    const float* __restrict__ c3w,
    const float* __restrict__ gk, const float* __restrict__ bk,
    const float* __restrict__ mk, const float* __restrict__ vk,
    unsigned short* __restrict__ ahi, unsigned short* __restrict__ alo,
    float* __restrict__ totb) {
  int bid = blockIdx.x;
  int tid = threadIdx.x;
  if (bid < 16) {
    int s = bid >> 2;
    int o = (bid & 3) * 16 + (tid >> 4);
    int kc = (tid & 15) * 4;
    float sc3 = g3[s] * rsqrtf(v3[s] + BN_EPS);
    float sc1 = g1[s] * rsqrtf(v1[s] + BN_EPS);
    float sck = gk[s] * rsqrtf(vk[s] + BN_EPS);
    float c0 = sc1 * c1w[s] + sck * c3w[s * 9 + 4];
    int oh = o >> 3, ow = o & 7;
    unsigned short H[4], L[4];
#pragma unroll
    for (int j = 0; j < 4; ++j) {
      int k = kc + j;
      int kh = k >> 3, kw = k & 7;
      float a = sc3 * fc3_w[(s * 64 + o) * 64 + k];
      int dy = kh - oh, dx = kw - ow;
      if (dy >= -1 && dy <= 1 && dx >= -1 && dx <= 1)
        a += (dy == 0 && dx == 0) ? c0 : sck * c3w[s * 9 + (dy + 1) * 3 + (dx + 1)];
      unsigned short h = bfbits(a);
      H[j] = h;
      L[j] = bfbits(a - bf2f(h));
    }
    size_t base = (size_t)(s * 64 + o) * 64 + kc;
    *(ushort4*)(ahi + base) = make_ushort4(H[0], H[1], H[2], H[3]);
    *(ushort4*)(alo + base) = make_ushort4(L[0], L[1], L[2], L[3]);
    if (bid == 0 && tid < 4) {
      int ss = tid;
      float s3 = g3[ss] * rsqrtf(v3[ss] + BN_EPS);
      float s1 = g1[ss] * rsqrtf(v1[ss] + BN_EPS);
      float sk = gk[ss] * rsqrtf(vk[ss] + BN_EPS);
      totb[ss] = (b3[ss] - m3[ss] * s3) + (b1[ss] - m1[ss] * s1) + (bk[ss] - mk[ss] * sk);
    }
    return;
  }
  // pool: wave w reduces plane (bid-16)*4 + w  (no LDS, no barriers)
  int w = tid >> 6, lane = tid & 63;
  int bc = (bid - 16) * 4 + w;
  const f32x4* xp = (const f32x4*)(x + (size_t)bc * 4096);
  float ssum = 0.f;
#pragma unroll
  for (int i = 0; i < 16; ++i) {
    f32x4 v = xp[i * 64 + lane];
    ssum += (v.x + v.y) + (v.z + v.w);
  }
#pragma unroll
  for (int m = 32; m >= 1; m >>= 1) ssum += __shfl_xor(ssum, m, 64);
  if (lane == 0) pooled[bc] = ssum * (1.f / 4096.f);
}

// ---------------- Kernel B: main — inline gate + GEMM + merge + store ----
// Grid 2048 = (b, hpi, cgh); wave = s (R5 structure). Gate computed
// redundantly per wave with shuffles (no barriers) while B-loads fly.
__global__ __launch_bounds__(256, 3) void main_kernel(
    const float* __restrict__ x,
    const unsigned short* __restrict__ ahi, const unsigned short* __restrict__ alo,
    const float* __restrict__ totb, const float* __restrict__ pooled,
    const float* __restrict__ fc1_w, const float* __restrict__ fc1_b,
    const float* __restrict__ fc2_w, const float* __restrict__ fc2_b,
    float* __restrict__ out) {
  int bid = blockIdx.x;
  int cgh = bid & 7;
  int hpi = (bid >> 3) & 7;
  int b   = bid >> 6;
  int tid = threadIdx.x;
  int s   = __builtin_amdgcn_readfirstlane(tid >> 6);
  int lane = tid & 63;
  int r16 = tid & 15;
  int g   = (tid >> 4) & 3;

  // ---- issue kt=0 B-loads up front ----
  int c_in = (cgh * 8 + (r16 & 7)) * 4 + s;
  const float* xbase = x + (size_t)(b * 256 + c_in) * 4096;
  f32x4 p0[4], p1[4];  // kt=0: [nt]
#pragma unroll
  for (int nt = 0; nt < 4; ++nt) {
    int wpi = nt * 2 + (r16 >> 3);
    const float* bp = xbase + (hpi * 8 + g) * 64 + wpi * 8;
    p0[nt] = *(const f32x4*)bp;
    p1[nt] = *(const f32x4*)(bp + 4);
  }

  // ---- gate (redundant per wave, barrier-free; hides B-load latency) ----
  float gmul[4];
  {
    const float* pb = pooled + b * 256;
    const float* wr = fc1_w + lane * 256;
    float a = fc1_b[lane];
#pragma unroll 8
    for (int j4 = 0; j4 < 64; ++j4) {
      f32x4 pv = *(const f32x4*)(pb + j4 * 4);
      f32x4 wv = *(const f32x4*)(wr + j4 * 4);
      a += pv.x * wv.x + pv.y * wv.y + pv.z * wv.z + pv.w * wv.w;
    }
    float hv = fmaxf(a, 0.f);

    int co[4];
    float ga[4];
#pragma unroll
    for (int nt = 0; nt < 4; ++nt) {
      co[nt] = (hpi * 32 + (nt * 2 + (r16 >> 3)) * 4 + s) * 64;
      ga[nt] = fc2_b[co[nt] >> 6];
    }
#pragma unroll 4
    for (int jq = 0; jq < 16; ++jq) {
      float h0 = __shfl(hv, jq * 4 + 0, 64);
      float h1 = __shfl(hv, jq * 4 + 1, 64);
      float h2 = __shfl(hv, jq * 4 + 2, 64);
      float h3 = __shfl(hv, jq * 4 + 3, 64);
#pragma unroll
      for (int nt = 0; nt < 4; ++nt) {
        f32x4 wv = *(const f32x4*)(fc2_w + co[nt] + jq * 4);
        ga[nt] += h0 * wv.x + h1 * wv.y + h2 * wv.z + h3 * wv.w;
      }
    }
#pragma unroll
    for (int nt = 0; nt < 4; ++nt) gmul[nt] = 1.f / (1.f + expf(-ga[nt]));
  }

  // ---- A fragments (L2-resident) ----
  short8 Ah[2][4], Al[2][4];  // [kt][ot]
#pragma unroll
  for (int ot = 0; ot < 4; ++ot)
#pragma unroll
    for (int kt = 0; kt < 2; ++kt) {
      size_t off = (size_t)(s * 64 + ot * 16 + r16) * 64 + kt * 32 + g * 8;
      Ah[kt][ot] = *(const short8*)(ahi + off);
      Al[kt][ot] = *(const short8*)(alo + off);
    }

  // ---- issue kt=1 B-loads (latency hides under kt=0 compute) ----
  f32x4 r0[4], r1[4];
#pragma unroll
  for (int nt = 0; nt < 4; ++nt) {
    int wpi = nt * 2 + (r16 >> 3);
    const float* bp = xbase + (hpi * 8 + 4 + g) * 64 + wpi * 8;
    r0[nt] = *(const f32x4*)bp;
    r1[nt] = *(const f32x4*)(bp + 4);
  }

  f32x4 acc[4][4];
#pragma unroll
  for (int i = 0; i < 4; ++i)
#pragma unroll
    for (int j = 0; j < 4; ++j) acc[i][j] = f32x4{0.f, 0.f, 0.f, 0.f};

  // ---- kt=0 convert + MFMA ----
#pragma unroll
  for (int nt = 0; nt < 4; ++nt) {
    float fv[8] = {p0[nt].x, p0[nt].y, p0[nt].z, p0[nt].w,
                   p1[nt].x, p1[nt].y, p1[nt].z, p1[nt].w};
    union { unsigned short u16[8]; short8 v; } BH, BL;
#pragma unroll
    for (int j = 0; j < 8; ++j) {
      unsigned short h = bfbits(fv[j]);
      BH.u16[j] = h;
      BL.u16[j] = bfbits(fv[j] - bf2f(h));
    }
#pragma unroll
    for (int ot = 0; ot < 4; ++ot) {
      acc[ot][nt] = __builtin_amdgcn_mfma_f32_16x16x32_bf16(Ah[0][ot], BH.v, acc[ot][nt], 0, 0, 0);
      acc[ot][nt] = __builtin_amdgcn_mfma_f32_16x16x32_bf16(Ah[0][ot], BL.v, acc[ot][nt], 0, 0, 0);
      acc[ot][nt] = __builtin_amdgcn_mfma_f32_16x16x32_bf16(Al[0][ot], BH.v, acc[ot][nt], 0, 0, 0);
    }
  }

  // ---- kt=1 convert + MFMA ----
#pragma unroll
  for (int nt = 0; nt < 4; ++nt) {
    float fv[8] = {r0[nt].x, r0[nt].y, r0[nt].z, r0[nt].w,
                   r1[nt].x, r1[nt].y, r1[nt].z, r1[nt].w};
    union { unsigned short u16[8]; short8 v; } BH, BL;
#pragma unroll
    for (int j = 0; j < 8; ++j) {
      unsigned short h = bfbits(fv[j]);
      BH.u16[j] = h;
      BL.u16[j] = bfbits(fv[j] - bf2f(h));
    }
#pragma unroll
    for (int ot = 0; ot < 4; ++ot) {
      acc[ot][nt] = __builtin_amdgcn_mfma_f32_16x16x32_bf16(Ah[1][ot], BH.v, acc[ot][nt], 0, 0, 0);
      acc[ot][nt] = __builtin_amdgcn_mfma_f32_16x16x32_bf16(Ah[1][ot], BL.v, acc[ot][nt], 0, 0, 0);
      acc[ot][nt] = __builtin_amdgcn_mfma_f32_16x16x32_bf16(Al[1][ot], BH.v, acc[ot][nt], 0, 0, 0);
    }
  }

  // ---- epilogue: direct nontemporal stores from C-frags ----
  float tb = totb[s];
#pragma unroll
  for (int nt = 0; nt < 4; ++nt) {
    int n2 = nt * 16 + r16;
    int c_out = hpi * 32 + (n2 >> 3) * 4 + s;
    float gm = gmul[nt];
    float* outb = out + (size_t)(b * 256 + c_out) * 4096 + cgh * 8 * 64 + (n2 & 7) * 8;
#pragma unroll
    for (int ot = 0; ot < 4; ++ot) {
      f32x4 a = acc[ot][nt];
      int hh = ot * 2 + (g >> 1);
      int wo = (g & 1) * 4;
      f32x4 o4 = {(a.x + tb) * gm, (a.y + tb) * gm,
                  (a.z + tb) * gm, (a.w + tb) * gm};
      __builtin_nontemporal_store(o4, (f32x4*)(outb + hh * 64 + wo));
    }
  }
}

extern "C" void kernel_launch(void* const* d_in, const int* in_sizes, int n_in,
                              void* d_out, int out_size, void* d_ws, size_t ws_size,
                              hipStream_t stream) {
  const float* x     = (const float*)d_in[0];
  const float* fc1_w = (const float*)d_in[1];
  const float* fc1_b = (const float*)d_in[2];
  const float* fc2_w = (const float*)d_in[3];
  const float* fc2_b = (const float*)d_in[4];
  const float* fc3_w = (const float*)d_in[5];
  const float* g3  = (const float*)d_in[6];
  const float* b3  = (const float*)d_in[7];
  const float* m3  = (const float*)d_in[8];
  const float* v3  = (const float*)d_in[9];
  const float* c1w = (const float*)d_in[10];
  const float* g1  = (const float*)d_in[11];
  const float* b1  = (const float*)d_in[12];
  const float* m1  = (const float*)d_in[13];
  const float* v1  = (const float*)d_in[14];
  const float* c3w = (const float*)d_in[15];
  const float* gk  = (const float*)d_in[16];
  const float* bk  = (const float*)d_in[17];
  const float* mk  = (const float*)d_in[18];
  const float* vk  = (const float*)d_in[19];
  float* out = (float*)d_out;

  // ws layout (16B-aligned): pooled 32KB | ahi 32KB | alo 32KB | totb
  float* pooled = (float*)d_ws;
  unsigned short* ahi = (unsigned short*)(pooled + 8192);
  unsigned short* alo = ahi + 16384;
  float* totb   = (float*)(alo + 16384);

  prep_pool_kernel<<<2064, 256, 0, stream>>>(x, pooled, fc3_w, g3, b3, m3, v3,
                                             c1w, g1, b1, m1, v1, c3w, gk, bk,
                                             mk, vk, ahi, alo, totb);
  main_kernel<<<2048, 256, 0, stream>>>(x, ahi, alo, totb, pooled,
                                        fc1_w, fc1_b, fc2_w, fc2_b, out);
}

// Round 10
// 97.841 us; speedup vs baseline: 1.3781x; 1.3781x over previous
//
#include <hip/hip_runtime.h>
#include <hip/hip_bf16.h>
#include <math.h>

#define BN_EPS 1e-5f

typedef __attribute__((ext_vector_type(8))) short short8;
typedef __attribute__((ext_vector_type(4))) float f32x4;

__device__ __forceinline__ unsigned short bfbits(float f) {
  __hip_bfloat16 h = __float2bfloat16(f);
  return *reinterpret_cast<unsigned short*>(&h);
}
__device__ __forceinline__ float bf2f(unsigned short u) {
  union { unsigned v; float f; } c; c.v = ((unsigned)u) << 16;
  return c.f;
}

// ---------------- Kernel A: prep (blocks 0..15) + pool (blocks 16..2063) ----
__global__ __launch_bounds__(256) void prep_pool_kernel(
    const float* __restrict__ x, float* __restrict__ pooled,
    const float* __restrict__ fc3_w,
    const float* __restrict__ g3, const float* __restrict__ b3,
    const float* __restrict__ m3, const float* __restrict__ v3,
    const float* __restrict__ c1w,
    const float* __restrict__ g1, const float* __restrict__ b1,
    const float* __restrict__ m1, const float* __restrict__ v1,
    const float* __restrict__ c3w,
    const float* __restrict__ gk, const float* __restrict__ bk,
    const float* __restrict__ mk, const float* __restrict__ vk,
    unsigned short* __restrict__ ahi, unsigned short* __restrict__ alo,
    float* __restrict__ totb) {
  int bid = blockIdx.x;
  int tid = threadIdx.x;
  if (bid < 16) {
    int s = bid >> 2;
    int o = (bid & 3) * 16 + (tid >> 4);
    int kc = (tid & 15) * 4;
    float sc3 = g3[s] * rsqrtf(v3[s] + BN_EPS);
    float sc1 = g1[s] * rsqrtf(v1[s] + BN_EPS);
    float sck = gk[s] * rsqrtf(vk[s] + BN_EPS);
    float c0 = sc1 * c1w[s] + sck * c3w[s * 9 + 4];
    int oh = o >> 3, ow = o & 7;
    unsigned short H[4], L[4];
#pragma unroll
    for (int j = 0; j < 4; ++j) {
      int k = kc + j;
      int kh = k >> 3, kw = k & 7;
      float a = sc3 * fc3_w[(s * 64 + o) * 64 + k];
      int dy = kh - oh, dx = kw - ow;
      if (dy >= -1 && dy <= 1 && dx >= -1 && dx <= 1)
        a += (dy == 0 && dx == 0) ? c0 : sck * c3w[s * 9 + (dy + 1) * 3 + (dx + 1)];
      unsigned short h = bfbits(a);
      H[j] = h;
      L[j] = bfbits(a - bf2f(h));
    }
    size_t base = (size_t)(s * 64 + o) * 64 + kc;
    *(ushort4*)(ahi + base) = make_ushort4(H[0], H[1], H[2], H[3]);
    *(ushort4*)(alo + base) = make_ushort4(L[0], L[1], L[2], L[3]);
    if (bid == 0 && tid < 4) {
      int ss = tid;
      float s3 = g3[ss] * rsqrtf(v3[ss] + BN_EPS);
      float s1 = g1[ss] * rsqrtf(v1[ss] + BN_EPS);
      float sk = gk[ss] * rsqrtf(vk[ss] + BN_EPS);
      totb[ss] = (b3[ss] - m3[ss] * s3) + (b1[ss] - m1[ss] * s1) + (bk[ss] - mk[ss] * sk);
    }
    return;
  }
  // pool: wave w reduces plane (bid-16)*4 + w (no LDS, no barriers)
  int w = tid >> 6, lane = tid & 63;
  int bc = (bid - 16) * 4 + w;
  const f32x4* xp = (const f32x4*)(x + (size_t)bc * 4096);
  float ssum = 0.f;
#pragma unroll
  for (int i = 0; i < 16; ++i) {
    f32x4 v = xp[i * 64 + lane];
    ssum += (v.x + v.y) + (v.z + v.w);
  }
#pragma unroll
  for (int m = 32; m >= 1; m >>= 1) ssum += __shfl_xor(ssum, m, 64);
  if (lane == 0) pooled[bc] = ssum * (1.f / 4096.f);
}

// ---------------- Kernel B: gate MLP (tiny, traffic-shared) ----------------
__global__ __launch_bounds__(256) void gate_kernel(const float* __restrict__ pooled,
                                                   const float* __restrict__ fc1_w,
                                                   const float* __restrict__ fc1_b,
                                                   const float* __restrict__ fc2_w,
                                                   const float* __restrict__ fc2_b,
                                                   float* __restrict__ gate) {
  int b = blockIdx.x;
  int tid = threadIdx.x;
  __shared__ float p[256];
  __shared__ float hbuf[64];
  p[tid] = pooled[b * 256 + tid];
  __syncthreads();
  if (tid < 64) {
    float a = fc1_b[tid];
    const float* wr = fc1_w + tid * 256;
#pragma unroll 8
    for (int c = 0; c < 256; ++c) a += p[c] * wr[c];
    hbuf[tid] = fmaxf(a, 0.f);
  }
  __syncthreads();
  float g = fc2_b[tid];
  const float* w2 = fc2_w + tid * 64;
#pragma unroll 8
  for (int j = 0; j < 64; ++j) g += hbuf[j] * w2[j];
  gate[b * 256 + tid] = 1.f / (1.f + expf(-g));
}

// ---------------- Kernel C: main — pipelined 4-unit blocks ---------------
// Grid 512 = (b, cgh, hp2); wave = s. Block loops u=0..3 (hpi = hp2*4+u).
// A-frags loaded once/block; two rolling B buffers; stores of unit u drain
// under unit u+1's loads/MFMAs. sched_barrier(0) fences unit boundaries.
__global__ __launch_bounds__(256, 2) void main_kernel(
    const float* __restrict__ x,
    const unsigned short* __restrict__ ahi, const unsigned short* __restrict__ alo,
    const float* __restrict__ totb, const float* __restrict__ gate,
    float* __restrict__ out) {
  int bid = blockIdx.x;
  int hp2 = bid & 1;
  int cgh = (bid >> 1) & 7;
  int b   = bid >> 4;
  int tid = threadIdx.x;
  int s   = __builtin_amdgcn_readfirstlane(tid >> 6);
  int r16 = tid & 15;
  int g   = (tid >> 4) & 3;

  int c_in = (cgh * 8 + (r16 & 7)) * 4 + s;
  const float* xbase = x + (size_t)(b * 256 + c_in) * 4096;
  float tb = totb[s];

  // ---- prologue: B loads for unit 0 (both kt) ----
  f32x4 q0[4][2], q1[4][2];  // [nt][quad]: kt=0 and kt=1
#pragma unroll
  for (int nt = 0; nt < 4; ++nt) {
    int wpi = nt * 2 + (r16 >> 3);
    const float* bp = xbase + (size_t)(hp2 * 32 + g) * 64 + wpi * 8;
    q0[nt][0] = *(const f32x4*)bp;
    q0[nt][1] = *(const f32x4*)(bp + 4);
    q1[nt][0] = *(const f32x4*)(bp + 256);       // +4 rows
    q1[nt][1] = *(const f32x4*)(bp + 256 + 4);
  }

  // ---- A fragments once per block (L2-resident) ----
  short8 Ah[2][4], Al[2][4];  // [kt][ot]
#pragma unroll
  for (int ot = 0; ot < 4; ++ot)
#pragma unroll
    for (int kt = 0; kt < 2; ++kt) {
      size_t off = (size_t)(s * 64 + ot * 16 + r16) * 64 + kt * 32 + g * 8;
      Ah[kt][ot] = *(const short8*)(ahi + off);
      Al[kt][ot] = *(const short8*)(alo + off);
    }

#pragma unroll
  for (int u = 0; u < 4; ++u) {
    int hpi = hp2 * 4 + u;

    // gate values for this unit (2 distinct addrs/wave -> cheap broadcast)
    float gmul[4];
#pragma unroll
    for (int nt = 0; nt < 4; ++nt)
      gmul[nt] = gate[b * 256 + hpi * 32 + (nt * 2 + (r16 >> 3)) * 4 + s];

    f32x4 acc[4][4];
#pragma unroll
    for (int i = 0; i < 4; ++i)
#pragma unroll
      for (int j = 0; j < 4; ++j) acc[i][j] = f32x4{0.f, 0.f, 0.f, 0.f};

    // ---- kt = 0: convert, prefetch next-unit kt0, MFMA ----
#pragma unroll
    for (int nt = 0; nt < 4; ++nt) {
      float fv[8] = {q0[nt][0].x, q0[nt][0].y, q0[nt][0].z, q0[nt][0].w,
                     q0[nt][1].x, q0[nt][1].y, q0[nt][1].z, q0[nt][1].w};
      union { unsigned short u16[8]; short8 v; } BH, BL;
#pragma unroll
      for (int j = 0; j < 8; ++j) {
        unsigned short h = bfbits(fv[j]);
        BH.u16[j] = h;
        BL.u16[j] = bfbits(fv[j] - bf2f(h));
      }
      if (u < 3) {  // prefetch next unit's kt0 into freed regs
        int wpi = nt * 2 + (r16 >> 3);
        const float* bp = xbase + (size_t)((hpi + 1) * 8 + g) * 64 + wpi * 8;
        q0[nt][0] = *(const f32x4*)bp;
        q0[nt][1] = *(const f32x4*)(bp + 4);
      }
#pragma unroll
      for (int ot = 0; ot < 4; ++ot) {
        acc[ot][nt] = __builtin_amdgcn_mfma_f32_16x16x32_bf16(Ah[0][ot], BH.v, acc[ot][nt], 0, 0, 0);
        acc[ot][nt] = __builtin_amdgcn_mfma_f32_16x16x32_bf16(Ah[0][ot], BL.v, acc[ot][nt], 0, 0, 0);
        acc[ot][nt] = __builtin_amdgcn_mfma_f32_16x16x32_bf16(Al[0][ot], BH.v, acc[ot][nt], 0, 0, 0);
      }
    }

    // ---- kt = 1: convert, prefetch next-unit kt1, MFMA ----
#pragma unroll
    for (int nt = 0; nt < 4; ++nt) {
      float fv[8] = {q1[nt][0].x, q1[nt][0].y, q1[nt][0].z, q1[nt][0].w,
                     q1[nt][1].x, q1[nt][1].y, q1[nt][1].z, q1[nt][1].w};
      union { unsigned short u16[8]; short8 v; } BH, BL;
#pragma unroll
      for (int j = 0; j < 8; ++j) {
        unsigned short h = bfbits(fv[j]);
        BH.u16[j] = h;
        BL.u16[j] = bfbits(fv[j] - bf2f(h));
      }
      if (u < 3) {
        int wpi = nt * 2 + (r16 >> 3);
        const float* bp = xbase + (size_t)((hpi + 1) * 8 + 4 + g) * 64 + wpi * 8;
        q1[nt][0] = *(const f32x4*)bp;
        q1[nt][1] = *(const f32x4*)(bp + 4);
      }
#pragma unroll
      for (int ot = 0; ot < 4; ++ot) {
        acc[ot][nt] = __builtin_amdgcn_mfma_f32_16x16x32_bf16(Ah[1][ot], BH.v, acc[ot][nt], 0, 0, 0);
        acc[ot][nt] = __builtin_amdgcn_mfma_f32_16x16x32_bf16(Ah[1][ot], BL.v, acc[ot][nt], 0, 0, 0);
        acc[ot][nt] = __builtin_amdgcn_mfma_f32_16x16x32_bf16(Al[1][ot], BH.v, acc[ot][nt], 0, 0, 0);
      }
    }

    // ---- epilogue: nontemporal stores for this unit ----
#pragma unroll
    for (int nt = 0; nt < 4; ++nt) {
      int n2 = nt * 16 + r16;
      int c_out = hpi * 32 + (n2 >> 3) * 4 + s;
      float gm = gmul[nt];
      float* outb = out + (size_t)(b * 256 + c_out) * 4096 + cgh * 8 * 64 + (n2 & 7) * 8;
#pragma unroll
      for (int ot = 0; ot < 4; ++ot) {
        f32x4 a = acc[ot][nt];
        int hh = ot * 2 + (g >> 1);
        int wo = (g & 1) * 4;
        f32x4 o4 = {(a.x + tb) * gm, (a.y + tb) * gm,
                    (a.z + tb) * gm, (a.w + tb) * gm};
        __builtin_nontemporal_store(o4, (f32x4*)(outb + hh * 64 + wo));
      }
    }

    __builtin_amdgcn_sched_barrier(0);  // fence unit boundary (keep pipeline shape)
  }
}

extern "C" void kernel_launch(void* const* d_in, const int* in_sizes, int n_in,
                              void* d_out, int out_size, void* d_ws, size_t ws_size,
                              hipStream_t stream) {
  const float* x     = (const float*)d_in[0];
  const float* fc1_w = (const float*)d_in[1];
  const float* fc1_b = (const float*)d_in[2];
  const float* fc2_w = (const float*)d_in[3];
  const float* fc2_b = (const float*)d_in[4];
  const float* fc3_w = (const float*)d_in[5];
  const float* g3  = (const float*)d_in[6];
  const float* b3  = (const float*)d_in[7];
  const float* m3  = (const float*)d_in[8];
  const float* v3  = (const float*)d_in[9];
  const float* c1w = (const float*)d_in[10];
  const float* g1  = (const float*)d_in[11];
  const float* b1  = (const float*)d_in[12];
  const float* m1  = (const float*)d_in[13];
  const float* v1  = (const float*)d_in[14];
  const float* c3w = (const float*)d_in[15];
  const float* gk  = (const float*)d_in[16];
  const float* bk  = (const float*)d_in[17];
  const float* mk  = (const float*)d_in[18];
  const float* vk  = (const float*)d_in[19];
  float* out = (float*)d_out;

  // ws layout (16B-aligned): pooled 32KB | gate 32KB | ahi 32KB | alo 32KB | totb
  float* pooled = (float*)d_ws;
  float* gate   = pooled + 8192;
  unsigned short* ahi = (unsigned short*)(gate + 8192);
  unsigned short* alo = ahi + 16384;
  float* totb   = (float*)(alo + 16384);

  prep_pool_kernel<<<2064, 256, 0, stream>>>(x, pooled, fc3_w, g3, b3, m3, v3,
                                             c1w, g1, b1, m1, v1, c3w, gk, bk,
                                             mk, vk, ahi, alo, totb);
  gate_kernel<<<32, 256, 0, stream>>>(pooled, fc1_w, fc1_b, fc2_w, fc2_b, gate);
  main_kernel<<<512, 256, 0, stream>>>(x, ahi, alo, totb, gate, out);
}

// Round 11
// 75.200 us; speedup vs baseline: 1.7930x; 1.3011x over previous
//
#include <hip/hip_runtime.h>
#include <hip/hip_bf16.h>
#include <math.h>

#define BN_EPS 1e-5f

typedef __attribute__((ext_vector_type(8))) short short8;
typedef __attribute__((ext_vector_type(4))) float f32x4;

__device__ __forceinline__ unsigned short bfbits(float f) {
  __hip_bfloat16 h = __float2bfloat16(f);
  return *reinterpret_cast<unsigned short*>(&h);
}
__device__ __forceinline__ float bf2f(unsigned short u) {
  union { unsigned v; float f; } c; c.v = ((unsigned)u) << 16;
  return c.f;
}

// ---------------- Kernel A: prep (blocks 0..15) + pool (blocks 16..2063) ----
__global__ __launch_bounds__(256) void prep_pool_kernel(
    const float* __restrict__ x, float* __restrict__ pooled,
    const float* __restrict__ fc3_w,
    const float* __restrict__ g3, const float* __restrict__ b3,
    const float* __restrict__ m3, const float* __restrict__ v3,
    const float* __restrict__ c1w,
    const float* __restrict__ g1, const float* __restrict__ b1,
    const float* __restrict__ m1, const float* __restrict__ v1,
    const float* __restrict__ c3w,
    const float* __restrict__ gk, const float* __restrict__ bk,
    const float* __restrict__ mk, const float* __restrict__ vk,
    unsigned short* __restrict__ ahi, unsigned short* __restrict__ alo,
    float* __restrict__ totb) {
  int bid = blockIdx.x;
  int tid = threadIdx.x;
  if (bid < 16) {
    int s = bid >> 2;
    int o = (bid & 3) * 16 + (tid >> 4);
    int kc = (tid & 15) * 4;
    float sc3 = g3[s] * rsqrtf(v3[s] + BN_EPS);
    float sc1 = g1[s] * rsqrtf(v1[s] + BN_EPS);
    float sck = gk[s] * rsqrtf(vk[s] + BN_EPS);
    float c0 = sc1 * c1w[s] + sck * c3w[s * 9 + 4];
    int oh = o >> 3, ow = o & 7;
    unsigned short H[4], L[4];
#pragma unroll
    for (int j = 0; j < 4; ++j) {
      int k = kc + j;
      int kh = k >> 3, kw = k & 7;
      float a = sc3 * fc3_w[(s * 64 + o) * 64 + k];
      int dy = kh - oh, dx = kw - ow;
      if (dy >= -1 && dy <= 1 && dx >= -1 && dx <= 1)
        a += (dy == 0 && dx == 0) ? c0 : sck * c3w[s * 9 + (dy + 1) * 3 + (dx + 1)];
      unsigned short h = bfbits(a);
      H[j] = h;
      L[j] = bfbits(a - bf2f(h));
    }
    size_t base = (size_t)(s * 64 + o) * 64 + kc;
    *(ushort4*)(ahi + base) = make_ushort4(H[0], H[1], H[2], H[3]);
    *(ushort4*)(alo + base) = make_ushort4(L[0], L[1], L[2], L[3]);
    if (bid == 0 && tid < 4) {
      int ss = tid;
      float s3 = g3[ss] * rsqrtf(v3[ss] + BN_EPS);
      float s1 = g1[ss] * rsqrtf(v1[ss] + BN_EPS);
      float sk = gk[ss] * rsqrtf(vk[ss] + BN_EPS);
      totb[ss] = (b3[ss] - m3[ss] * s3) + (b1[ss] - m1[ss] * s1) + (bk[ss] - mk[ss] * sk);
    }
    return;
  }
  int w = tid >> 6, lane = tid & 63;
  int bc = (bid - 16) * 4 + w;
  const f32x4* xp = (const f32x4*)(x + (size_t)bc * 4096);
  float ssum = 0.f;
#pragma unroll
  for (int i = 0; i < 16; ++i) {
    f32x4 v = xp[i * 64 + lane];
    ssum += (v.x + v.y) + (v.z + v.w);
  }
#pragma unroll
  for (int m = 32; m >= 1; m >>= 1) ssum += __shfl_xor(ssum, m, 64);
  if (lane == 0) pooled[bc] = ssum * (1.f / 4096.f);
}

// ---------------- Kernel B: gate MLP (tiny, traffic-shared) ----------------
__global__ __launch_bounds__(256) void gate_kernel(const float* __restrict__ pooled,
                                                   const float* __restrict__ fc1_w,
                                                   const float* __restrict__ fc1_b,
                                                   const float* __restrict__ fc2_w,
                                                   const float* __restrict__ fc2_b,
                                                   float* __restrict__ gate) {
  int b = blockIdx.x;
  int tid = threadIdx.x;
  __shared__ float p[256];
  __shared__ float hbuf[64];
  p[tid] = pooled[b * 256 + tid];
  __syncthreads();
  if (tid < 64) {
    float a = fc1_b[tid];
    const float* wr = fc1_w + tid * 256;
#pragma unroll 8
    for (int c = 0; c < 256; ++c) a += p[c] * wr[c];
    hbuf[tid] = fmaxf(a, 0.f);
  }
  __syncthreads();
  float g = fc2_b[tid];
  const float* w2 = fc2_w + tid * 64;
#pragma unroll 8
  for (int j = 0; j < 64; ++j) g += hbuf[j] * w2[j];
  gate[b * 256 + tid] = 1.f / (1.f + expf(-g));
}

// ---------------- Kernel C: main — LDS-staged, conversion-free MFMA loop ---
// Grid 2048 = (b, hpi, cgh). Block = 512 thr = 8 waves = (s x o-half).
// Stage: 32ch x 8row x 64col fp32 tile read LANE-CONTIGUOUS (1KB/wave-instr),
// converted once to bf16 hi/lo, ds_written to slot-padded LDS (stride 520 ush,
// slot = s*8+j -> wave's 8 channels 4 banks apart; uniform-optimal patterns).
// Then: pure ds_read_b128 + MFMA (no VALU converts), NT stores.
__global__ __launch_bounds__(512, 4) void main_kernel(
    const float* __restrict__ x,
    const unsigned short* __restrict__ ahi, const unsigned short* __restrict__ alo,
    const float* __restrict__ totb, const float* __restrict__ gate,
    float* __restrict__ out) {
  __shared__ unsigned short xs[33280];  // hi plane [0,16640), lo plane [16640,33280)

  int bid = blockIdx.x;
  int cgh = bid & 7;
  int hpi = (bid >> 3) & 7;
  int b   = bid >> 6;
  int tid = threadIdx.x;
  int wv  = tid >> 6;
  int s    = __builtin_amdgcn_readfirstlane(wv & 3);
  int half = __builtin_amdgcn_readfirstlane(wv >> 2);
  int r16 = tid & 15;
  int g   = (tid >> 4) & 3;

  // ---- stage: 8 batched contiguous loads per thread ----
  f32x4 gbuf[8];
#pragma unroll
  for (int i = 0; i < 8; ++i) {
    int flat = i * 512 + tid;            // f32x4 units over the 64KB tile
    int slot = flat >> 7;                // 0..31
    int off  = flat & 127;
    int row  = off >> 4, w4 = off & 15;
    int c = cgh * 32 + (slot & 7) * 4 + (slot >> 3);
    gbuf[i] = *(const f32x4*)(x + (size_t)(b * 256 + c) * 4096 + (hpi * 8 + row) * 64 + w4 * 4);
  }

  // ---- A fragments + gate + bias issued while staging loads fly ----
  short8 Ah[2][2], Al[2][2];  // [kt][oti], rows (half*2+oti)*16+r16
#pragma unroll
  for (int oti = 0; oti < 2; ++oti)
#pragma unroll
    for (int kt = 0; kt < 2; ++kt) {
      size_t off = (size_t)(s * 64 + (half * 2 + oti) * 16 + r16) * 64 + kt * 32 + g * 8;
      Ah[kt][oti] = *(const short8*)(ahi + off);
      Al[kt][oti] = *(const short8*)(alo + off);
    }
  float gmul[4];
#pragma unroll
  for (int nt = 0; nt < 4; ++nt)
    gmul[nt] = gate[b * 256 + hpi * 32 + (nt * 2 + (r16 >> 3)) * 4 + s];
  float tb = totb[s];

  // ---- convert + ds_write (hi/lo planes) ----
#pragma unroll
  for (int i = 0; i < 8; ++i) {
    int flat = i * 512 + tid;
    int slot = flat >> 7;
    int off  = flat & 127;
    int row  = off >> 4, w4 = off & 15;
    float fv[4] = {gbuf[i].x, gbuf[i].y, gbuf[i].z, gbuf[i].w};
    ushort4 H, L;
    unsigned short h0 = bfbits(fv[0]), h1 = bfbits(fv[1]), h2 = bfbits(fv[2]), h3 = bfbits(fv[3]);
    H = make_ushort4(h0, h1, h2, h3);
    L = make_ushort4(bfbits(fv[0] - bf2f(h0)), bfbits(fv[1] - bf2f(h1)),
                     bfbits(fv[2] - bf2f(h2)), bfbits(fv[3] - bf2f(h3)));
    int base = slot * 520 + row * 64 + w4 * 4;
    *(ushort4*)&xs[base] = H;
    *(ushort4*)&xs[16640 + base] = L;
  }

  __syncthreads();

  // ---- MFMA loop: pure ds_read + MFMA ----
  f32x4 acc[2][4];
#pragma unroll
  for (int i = 0; i < 2; ++i)
#pragma unroll
    for (int j = 0; j < 4; ++j) acc[i][j] = f32x4{0.f, 0.f, 0.f, 0.f};

  int jch = r16 & 7;                     // channel index within shareset
#pragma unroll
  for (int kt = 0; kt < 2; ++kt)
#pragma unroll
    for (int nt = 0; nt < 4; ++nt) {
      int wpi = nt * 2 + (r16 >> 3);
      int addr = (s * 8 + jch) * 520 + (kt * 4 + g) * 64 + wpi * 8;
      short8 BH = *(const short8*)&xs[addr];
      short8 BL = *(const short8*)&xs[16640 + addr];
#pragma unroll
      for (int oti = 0; oti < 2; ++oti) {
        acc[oti][nt] = __builtin_amdgcn_mfma_f32_16x16x32_bf16(Ah[kt][oti], BH, acc[oti][nt], 0, 0, 0);
        acc[oti][nt] = __builtin_amdgcn_mfma_f32_16x16x32_bf16(Ah[kt][oti], BL, acc[oti][nt], 0, 0, 0);
        acc[oti][nt] = __builtin_amdgcn_mfma_f32_16x16x32_bf16(Al[kt][oti], BH, acc[oti][nt], 0, 0, 0);
      }
    }

  // ---- epilogue: NT stores. o = (half*2+oti)*16 + g*4 + r, col n2 = nt*16+r16
#pragma unroll
  for (int nt = 0; nt < 4; ++nt) {
    int n2 = nt * 16 + r16;
    int c_out = hpi * 32 + (n2 >> 3) * 4 + s;
    float gm = gmul[nt];
    float* outb = out + (size_t)(b * 256 + c_out) * 4096 + cgh * 8 * 64 + (n2 & 7) * 8;
#pragma unroll
    for (int oti = 0; oti < 2; ++oti) {
      f32x4 a = acc[oti][nt];
      int hh = (half * 2 + oti) * 2 + (g >> 1);
      int wo = (g & 1) * 4;
      f32x4 o4 = {(a.x + tb) * gm, (a.y + tb) * gm,
                  (a.z + tb) * gm, (a.w + tb) * gm};
      __builtin_nontemporal_store(o4, (f32x4*)(outb + hh * 64 + wo));
    }
  }
}

extern "C" void kernel_launch(void* const* d_in, const int* in_sizes, int n_in,
                              void* d_out, int out_size, void* d_ws, size_t ws_size,
                              hipStream_t stream) {
  const float* x     = (const float*)d_in[0];
  const float* fc1_w = (const float*)d_in[1];
  const float* fc1_b = (const float*)d_in[2];
  const float* fc2_w = (const float*)d_in[3];
  const float* fc2_b = (const float*)d_in[4];
  const float* fc3_w = (const float*)d_in[5];
  const float* g3  = (const float*)d_in[6];
  const float* b3  = (const float*)d_in[7];
  const float* m3  = (const float*)d_in[8];
  const float* v3  = (const float*)d_in[9];
  const float* c1w = (const float*)d_in[10];
  const float* g1  = (const float*)d_in[11];
  const float* b1  = (const float*)d_in[12];
  const float* m1  = (const float*)d_in[13];
  const float* v1  = (const float*)d_in[14];
  const float* c3w = (const float*)d_in[15];
  const float* gk  = (const float*)d_in[16];
  const float* bk  = (const float*)d_in[17];
  const float* mk  = (const float*)d_in[18];
  const float* vk  = (const float*)d_in[19];
  float* out = (float*)d_out;

  // ws layout (16B-aligned): pooled 32KB | gate 32KB | ahi 32KB | alo 32KB | totb
  float* pooled = (float*)d_ws;
  float* gate   = pooled + 8192;
  unsigned short* ahi = (unsigned short*)(gate + 8192);
  unsigned short* alo = ahi + 16384;
  float* totb   = (float*)(alo + 16384);

  prep_pool_kernel<<<2064, 256, 0, stream>>>(x, pooled, fc3_w, g3, b3, m3, v3,
                                             c1w, g1, b1, m1, v1, c3w, gk, bk,
                                             mk, vk, ahi, alo, totb);
  gate_kernel<<<32, 256, 0, stream>>>(pooled, fc1_w, fc1_b, fc2_w, fc2_b, gate);
  main_kernel<<<2048, 512, 0, stream>>>(x, ahi, alo, totb, gate, out);
}